// Round 1
// baseline (547.034 us; speedup 1.0000x reference)
//
#include <hip/hip_runtime.h>
#include <math.h>

// Problem constants
constexpr int NB = 2;        // batch
constexpr int LQ = 2048;     // sequence length
constexpr int DD = 512;      // model dim
constexpr int PPL = 16;      // planes per set
constexpr int TPP = 64;      // total planes (S*P)
constexpr int NC = 32;       // chunks for scan
constexpr int TC = LQ / NC;  // chunk length = 64
constexpr float PI_F = 3.14159265358979323846f;

// ---------------- fp32 tiled GEMM: C = act(A@W + bias) [+ resid] ----------------
// A [M,K] rm, W [K,N] rm, 64x64 block tile, 256 thr, 4x4 microtile, BK=16
template<int ACT, int RESID>
__global__ __launch_bounds__(256) void gemm_kernel(
    const float* __restrict__ A, const float* __restrict__ W,
    const float* __restrict__ bias, const float* __restrict__ resid,
    float* __restrict__ Cout, int M, int N, int K)
{
    __shared__ float As[16][68];  // transposed A tile [k][m]
    __shared__ float Ws[16][68];  // W tile [k][n]
    const int tid = threadIdx.x;
    const int tx = tid & 15, ty = tid >> 4;
    const int row0 = blockIdx.y * 64, col0 = blockIdx.x * 64;
    const int am = tid >> 2, ak = (tid & 3) << 2;   // A: 1 float4 per thread
    const int wk = tid >> 4, wn = (tid & 15) << 2;  // W: 1 float4 per thread
    float acc[4][4] = {};
    for (int k0 = 0; k0 < K; k0 += 16) {
        float4 av = *(const float4*)(A + (size_t)(row0 + am) * K + k0 + ak);
        float4 wv = *(const float4*)(W + (size_t)(k0 + wk) * N + col0 + wn);
        __syncthreads();
        As[ak + 0][am] = av.x;
        As[ak + 1][am] = av.y;
        As[ak + 2][am] = av.z;
        As[ak + 3][am] = av.w;
        *(float4*)&Ws[wk][wn] = wv;
        __syncthreads();
#pragma unroll
        for (int k = 0; k < 16; ++k) {
            float4 a4 = *(const float4*)&As[k][ty << 2];
            float4 w4 = *(const float4*)&Ws[k][tx << 2];
            float a[4] = {a4.x, a4.y, a4.z, a4.w};
            float w[4] = {w4.x, w4.y, w4.z, w4.w};
#pragma unroll
            for (int i = 0; i < 4; ++i)
#pragma unroll
                for (int j = 0; j < 4; ++j)
                    acc[i][j] = fmaf(a[i], w[j], acc[i][j]);
        }
    }
#pragma unroll
    for (int i = 0; i < 4; ++i) {
        const int row = row0 + (ty << 2) + i;
#pragma unroll
        for (int j = 0; j < 4; ++j) {
            const int col = col0 + (tx << 2) + j;
            float v = acc[i][j] + bias[col];
            if (ACT == 1) v = 0.5f * v * (1.0f + erff(v * 0.70710678118654752f));
            if (RESID) v += resid[(size_t)row * N + col];
            Cout[(size_t)row * N + col] = v;
        }
    }
}

// ---------------- phase GEMM: OUT[row][p][{cos,sin}] = phasor(tanh(H@W2+b2)*pi) ----------------
// N fixed = TPP = 64 (single block column). ISQ: scale by softmax(set_weights)[p/16].
template<int ISQ>
__global__ __launch_bounds__(256) void phase_kernel(
    const float* __restrict__ H, const float* __restrict__ W2,
    const float* __restrict__ b2, const float* __restrict__ sw,
    float* __restrict__ OUT, int M, int K)
{
    __shared__ float As[16][68];
    __shared__ float Ws[16][68];
    const int tid = threadIdx.x;
    const int tx = tid & 15, ty = tid >> 4;
    const int row0 = blockIdx.x * 64;
    const int am = tid >> 2, ak = (tid & 3) << 2;
    const int wk = tid >> 4, wn = (tid & 15) << 2;
    float acc[4][4] = {};
    for (int k0 = 0; k0 < K; k0 += 16) {
        float4 av = *(const float4*)(H + (size_t)(row0 + am) * K + k0 + ak);
        float4 wv = *(const float4*)(W2 + (size_t)(k0 + wk) * TPP + wn);
        __syncthreads();
        As[ak + 0][am] = av.x;
        As[ak + 1][am] = av.y;
        As[ak + 2][am] = av.z;
        As[ak + 3][am] = av.w;
        *(float4*)&Ws[wk][wn] = wv;
        __syncthreads();
#pragma unroll
        for (int k = 0; k < 16; ++k) {
            float4 a4 = *(const float4*)&As[k][ty << 2];
            float4 w4 = *(const float4*)&Ws[k][tx << 2];
            float a[4] = {a4.x, a4.y, a4.z, a4.w};
            float w[4] = {w4.x, w4.y, w4.z, w4.w};
#pragma unroll
            for (int i = 0; i < 4; ++i)
#pragma unroll
                for (int j = 0; j < 4; ++j)
                    acc[i][j] = fmaf(a[i], w[j], acc[i][j]);
        }
    }
    float wsm[4] = {1.f, 1.f, 1.f, 1.f};
    if (ISQ) {
        float s0 = sw[0], s1 = sw[1], s2 = sw[2], s3 = sw[3];
        float m = fmaxf(fmaxf(s0, s1), fmaxf(s2, s3));
        float e0 = expf(s0 - m), e1 = expf(s1 - m), e2 = expf(s2 - m), e3 = expf(s3 - m);
        float inv = 1.0f / (e0 + e1 + e2 + e3);
        wsm[0] = e0 * inv; wsm[1] = e1 * inv; wsm[2] = e2 * inv; wsm[3] = e3 * inv;
    }
#pragma unroll
    for (int i = 0; i < 4; ++i) {
        const int row = row0 + (ty << 2) + i;
#pragma unroll
        for (int j = 0; j < 4; ++j) {
            const int p = (tx << 2) + j;
            float u = acc[i][j] + b2[p];
            float ph = tanhf(u) * PI_F;
            float sp, cp;
            sincosf(ph, &sp, &cp);
            const float wg = ISQ ? wsm[p >> 4] : 1.0f;
            OUT[((size_t)row * TPP + p) * 2 + 0] = cp * wg;
            OUT[((size_t)row * TPP + p) * 2 + 1] = sp * wg;
        }
    }
}

// ---------------- pass A: per-chunk plane sums S[b][c][ri][p][d] ----------------
__global__ __launch_bounds__(256) void passA_kernel(
    const float* __restrict__ CK, const float* __restrict__ V,
    float* __restrict__ S)
{
    const int d = blockIdx.x * 256 + threadIdx.x;
    const int c = blockIdx.y, b = blockIdx.z;
    const int l0 = c * TC;
    float mre[TPP], mim[TPP];
#pragma unroll
    for (int p = 0; p < TPP; ++p) { mre[p] = 0.f; mim[p] = 0.f; }
    const float* ck = CK + (size_t)(b * LQ + l0) * TPP * 2;
    const float* vp = V + (size_t)(b * LQ + l0) * DD + d;
#pragma unroll 1
    for (int t = 0; t < TC; ++t) {
        const float v = vp[(size_t)t * DD];
        const float* ckt = ck + t * TPP * 2;
#pragma unroll
        for (int p = 0; p < TPP; ++p) {
            mre[p] = fmaf(ckt[2 * p + 0], v, mre[p]);
            mim[p] = fmaf(ckt[2 * p + 1], v, mim[p]);
        }
    }
    float* sp = S + (size_t)(b * NC + c) * 2 * TPP * DD + d;
#pragma unroll
    for (int p = 0; p < TPP; ++p) {
        sp[(size_t)p * DD] = mre[p];
        sp[(size_t)(TPP + p) * DD] = mim[p];
    }
}

// ---------------- exclusive prefix over chunks (in place) ----------------
__global__ __launch_bounds__(256) void prefix_kernel(float* __restrict__ S)
{
    const int gid = blockIdx.x * 256 + threadIdx.x;  // ((b*2+ri)*TPP+p)*DD+d
    const int d = gid & (DD - 1);
    int rest = gid >> 9;
    const int p = rest & (TPP - 1); rest >>= 6;
    const int ri = rest & 1;
    const int b = rest >> 1;
    float run = 0.f;
    for (int c = 0; c < NC; ++c) {
        const size_t idx = ((size_t)(b * NC + c) * 2 + ri) * TPP * DD + (size_t)p * DD + d;
        const float v = S[idx];
        S[idx] = run;
        run += v;
    }
}

// ---------------- pass C: local scan with carry-in, emit r ----------------
__global__ __launch_bounds__(256) void passC_kernel(
    const float* __restrict__ CK, const float* __restrict__ CQ,
    const float* __restrict__ V, const float* __restrict__ S,
    float* __restrict__ R)
{
    const int d = blockIdx.x * 256 + threadIdx.x;
    const int c = blockIdx.y, b = blockIdx.z;
    const int l0 = c * TC;
    float mre[TPP], mim[TPP];
    const float* sp = S + (size_t)(b * NC + c) * 2 * TPP * DD + d;
#pragma unroll
    for (int p = 0; p < TPP; ++p) {
        mre[p] = sp[(size_t)p * DD];
        mim[p] = sp[(size_t)(TPP + p) * DD];
    }
    const float* ck = CK + (size_t)(b * LQ + l0) * TPP * 2;
    const float* cq = CQ + (size_t)(b * LQ + l0) * TPP * 2;
    const float* vp = V + (size_t)(b * LQ + l0) * DD + d;
    float* rp = R + (size_t)(b * LQ + l0) * DD + d;
#pragma unroll 1
    for (int t = 0; t < TC; ++t) {
        const float v = vp[(size_t)t * DD];
        const float* ckt = ck + t * TPP * 2;
        const float* cqt = cq + t * TPP * 2;
        float a0 = 0.f, a1 = 0.f, a2 = 0.f, a3 = 0.f;
#pragma unroll
        for (int p = 0; p < TPP; p += 2) {
            mre[p] = fmaf(ckt[2 * p + 0], v, mre[p]);
            mim[p] = fmaf(ckt[2 * p + 1], v, mim[p]);
            a0 = fmaf(cqt[2 * p + 0], mre[p], a0);
            a1 = fmaf(cqt[2 * p + 1], mim[p], a1);
            mre[p + 1] = fmaf(ckt[2 * p + 2], v, mre[p + 1]);
            mim[p + 1] = fmaf(ckt[2 * p + 3], v, mim[p + 1]);
            a2 = fmaf(cqt[2 * p + 2], mre[p + 1], a2);
            a3 = fmaf(cqt[2 * p + 3], mim[p + 1], a3);
        }
        rp[(size_t)t * DD] = (a0 + a1) + (a2 + a3);
    }
}

// ---------------- position norm + LayerNorm ----------------
__global__ __launch_bounds__(256) void ln_kernel(
    const float* __restrict__ R, const float* __restrict__ g,
    const float* __restrict__ be, float* __restrict__ YN)
{
    const int row = blockIdx.x;          // b*LQ + l
    const int l = row & (LQ - 1);
    const int tid = threadIdx.x;
    const float pscale = rsqrtf((float)((l + 1) * PPL));
    float y0 = R[(size_t)row * DD + tid] * pscale;
    float y1 = R[(size_t)row * DD + 256 + tid] * pscale;
    float s = y0 + y1;
    float q = y0 * y0 + y1 * y1;
#pragma unroll
    for (int off = 32; off >= 1; off >>= 1) {
        s += __shfl_xor(s, off, 64);
        q += __shfl_xor(q, off, 64);
    }
    __shared__ float rs[4], rq[4];
    const int wid = tid >> 6, lane = tid & 63;
    if (lane == 0) { rs[wid] = s; rq[wid] = q; }
    __syncthreads();
    const float ts = rs[0] + rs[1] + rs[2] + rs[3];
    const float tq = rq[0] + rq[1] + rq[2] + rq[3];
    const float mu = ts * (1.0f / DD);
    float var = tq * (1.0f / DD) - mu * mu;
    const float rstd = rsqrtf(var + 1e-5f);
    YN[(size_t)row * DD + tid] = (y0 - mu) * rstd * g[tid] + be[tid];
    YN[(size_t)row * DD + 256 + tid] = (y1 - mu) * rstd * g[tid + 256] + be[tid + 256];
}

extern "C" void kernel_launch(void* const* d_in, const int* in_sizes, int n_in,
                              void* d_out, int out_size, void* d_ws, size_t ws_size,
                              hipStream_t stream)
{
    const float* x   = (const float*)d_in[0];
    const float* sw  = (const float*)d_in[1];
    const float* kw1 = (const float*)d_in[2];
    const float* kb1 = (const float*)d_in[3];
    const float* kw2 = (const float*)d_in[4];
    const float* kb2 = (const float*)d_in[5];
    const float* qw1 = (const float*)d_in[6];
    const float* qb1 = (const float*)d_in[7];
    const float* qw2 = (const float*)d_in[8];
    const float* qb2 = (const float*)d_in[9];
    const float* vw  = (const float*)d_in[10];
    const float* vb  = (const float*)d_in[11];
    const float* lng = (const float*)d_in[12];
    const float* lnb = (const float*)d_in[13];
    const float* ow  = (const float*)d_in[14];
    const float* ob  = (const float*)d_in[15];
    float* out = (float*)d_out;

    float* ws = (float*)d_ws;
    const size_t MR = (size_t)NB * LQ;  // 4096 rows
    float* hk  = ws;                       // MR*DD
    float* hq  = hk + MR * DD;
    float* Vb  = hq + MR * DD;
    float* CKb = Vb + MR * DD;             // MR*TPP*2
    float* CQb = CKb + MR * TPP * 2;
    float* Sb  = CQb + MR * TPP * 2;       // NB*NC*2*TPP*DD
    float* Rb  = Sb + (size_t)NB * NC * 2 * TPP * DD;
    float* YN  = Rb + MR * DD;

    const dim3 blk(256);
    const dim3 g1(DD / 64, MR / 64);
    hipLaunchKernelGGL((gemm_kernel<1, 0>), g1, blk, 0, stream, x, kw1, kb1, nullptr, hk, (int)MR, DD, DD);
    hipLaunchKernelGGL((gemm_kernel<1, 0>), g1, blk, 0, stream, x, qw1, qb1, nullptr, hq, (int)MR, DD, DD);
    hipLaunchKernelGGL((gemm_kernel<0, 0>), g1, blk, 0, stream, x, vw, vb, nullptr, Vb, (int)MR, DD, DD);
    const dim3 gp(MR / 64);
    hipLaunchKernelGGL((phase_kernel<0>), gp, blk, 0, stream, hk, kw2, kb2, nullptr, CKb, (int)MR, DD);
    hipLaunchKernelGGL((phase_kernel<1>), gp, blk, 0, stream, hq, qw2, qb2, sw, CQb, (int)MR, DD);
    const dim3 ga(DD / 256, NC, NB);
    hipLaunchKernelGGL(passA_kernel, ga, blk, 0, stream, CKb, Vb, Sb);
    hipLaunchKernelGGL(prefix_kernel, dim3((NB * 2 * TPP * DD) / 256), blk, 0, stream, Sb);
    hipLaunchKernelGGL(passC_kernel, ga, blk, 0, stream, CKb, CQb, Vb, Sb, Rb);
    hipLaunchKernelGGL(ln_kernel, dim3((unsigned)MR), blk, 0, stream, Rb, lng, lnb, YN);
    hipLaunchKernelGGL((gemm_kernel<0, 1>), g1, blk, 0, stream, YN, ow, ob, x, out, (int)MR, DD, DD);
}

// Round 3
// 318.264 us; speedup vs baseline: 1.7188x; 1.7188x over previous
//
#include <hip/hip_runtime.h>
#include <math.h>

// Problem constants
constexpr int NB = 2;        // batch
constexpr int LQ = 2048;     // sequence length
constexpr int DD = 512;      // model dim
constexpr int PPL = 16;      // planes per set
constexpr int TPP = 64;      // total planes (S*P)
constexpr int FF = 128;      // feature dim = 2*TPP (cos,sin interleaved)
constexpr int NC = 32;       // chunks
constexpr int TC = 64;       // chunk length
constexpr float PI_F = 3.14159265358979323846f;

typedef __attribute__((ext_vector_type(4))) float f32x4;
typedef __attribute__((ext_vector_type(8))) short bf16x8;

static __device__ __forceinline__ unsigned short f2bf(float x) {
    union { float f; unsigned u; } v; v.f = x;
    unsigned r = v.u + 0x7fff + ((v.u >> 16) & 1);
    return (unsigned short)(r >> 16);
}

// ---------------- fp32 tiled GEMM: C = act(A@W + bias) [+ resid] ----------------
// VT=1: instead of fp32 C, emit Vt[b][c][d][t] bf16 (value tensor, t-contiguous)
template<int ACT, int RESID, int VT>
__global__ __launch_bounds__(256) void gemm_kernel(
    const float* __restrict__ A, const float* __restrict__ W,
    const float* __restrict__ bias, const float* __restrict__ resid,
    float* __restrict__ Cout, unsigned short* __restrict__ vt,
    int M, int N, int K)
{
    __shared__ float As[16][68];
    __shared__ float Ws[16][68];
    const int tid = threadIdx.x;
    const int tx = tid & 15, ty = tid >> 4;
    const int row0 = blockIdx.y * 64, col0 = blockIdx.x * 64;
    const int am = tid >> 2, ak = (tid & 3) << 2;
    const int wk = tid >> 4, wn = (tid & 15) << 2;
    float acc[4][4] = {};
    for (int k0 = 0; k0 < K; k0 += 16) {
        float4 av = *(const float4*)(A + (size_t)(row0 + am) * K + k0 + ak);
        float4 wv = *(const float4*)(W + (size_t)(k0 + wk) * N + col0 + wn);
        __syncthreads();
        As[ak + 0][am] = av.x;
        As[ak + 1][am] = av.y;
        As[ak + 2][am] = av.z;
        As[ak + 3][am] = av.w;
        *(float4*)&Ws[wk][wn] = wv;
        __syncthreads();
#pragma unroll
        for (int k = 0; k < 16; ++k) {
            float4 a4 = *(const float4*)&As[k][ty << 2];
            float4 w4 = *(const float4*)&Ws[k][tx << 2];
            float a[4] = {a4.x, a4.y, a4.z, a4.w};
            float w[4] = {w4.x, w4.y, w4.z, w4.w};
#pragma unroll
            for (int i = 0; i < 4; ++i)
#pragma unroll
                for (int j = 0; j < 4; ++j)
                    acc[i][j] = fmaf(a[i], w[j], acc[i][j]);
        }
    }
#pragma unroll
    for (int i = 0; i < 4; ++i) {
        const int row = row0 + (ty << 2) + i;
#pragma unroll
        for (int j = 0; j < 4; ++j) {
            const int col = col0 + (tx << 2) + j;
            float v = acc[i][j] + bias[col];
            if (ACT == 1) v = 0.5f * v * (1.0f + erff(v * 0.70710678118654752f));
            if (RESID) v += resid[(size_t)row * N + col];
            if (VT) {
                const int b = row >> 11, l = row & (LQ - 1);
                const int c = l >> 6, t = l & 63;
                vt[((size_t)((b * NC + c) * DD) + col) * TC + t] = f2bf(v);
            } else {
                Cout[(size_t)row * N + col] = v;
            }
        }
    }
}

// ---------------- phase GEMM: tanh(H@W2+b2)*pi -> cos/sin bf16 features ----------------
// ISQ=0 (K): write CKb[row][f] and CKt[b][c][f][t].  ISQ=1 (Q): write CQb[row][f], softmax(sw) folded.
template<int ISQ>
__global__ __launch_bounds__(256) void phase_kernel(
    const float* __restrict__ H, const float* __restrict__ W2,
    const float* __restrict__ b2, const float* __restrict__ sw,
    unsigned short* __restrict__ FROW, unsigned short* __restrict__ FT,
    int M, int K)
{
    __shared__ float As[16][68];
    __shared__ float Ws[16][68];
    const int tid = threadIdx.x;
    const int tx = tid & 15, ty = tid >> 4;
    const int row0 = blockIdx.x * 64;
    const int am = tid >> 2, ak = (tid & 3) << 2;
    const int wk = tid >> 4, wn = (tid & 15) << 2;
    float acc[4][4] = {};
    for (int k0 = 0; k0 < K; k0 += 16) {
        float4 av = *(const float4*)(H + (size_t)(row0 + am) * K + k0 + ak);
        float4 wv = *(const float4*)(W2 + (size_t)(k0 + wk) * TPP + wn);
        __syncthreads();
        As[ak + 0][am] = av.x;
        As[ak + 1][am] = av.y;
        As[ak + 2][am] = av.z;
        As[ak + 3][am] = av.w;
        *(float4*)&Ws[wk][wn] = wv;
        __syncthreads();
#pragma unroll
        for (int k = 0; k < 16; ++k) {
            float4 a4 = *(const float4*)&As[k][ty << 2];
            float4 w4 = *(const float4*)&Ws[k][tx << 2];
            float a[4] = {a4.x, a4.y, a4.z, a4.w};
            float w[4] = {w4.x, w4.y, w4.z, w4.w};
#pragma unroll
            for (int i = 0; i < 4; ++i)
#pragma unroll
                for (int j = 0; j < 4; ++j)
                    acc[i][j] = fmaf(a[i], w[j], acc[i][j]);
        }
    }
    float wsm[4] = {1.f, 1.f, 1.f, 1.f};
    if (ISQ) {
        float s0 = sw[0], s1 = sw[1], s2 = sw[2], s3 = sw[3];
        float m = fmaxf(fmaxf(s0, s1), fmaxf(s2, s3));
        float e0 = expf(s0 - m), e1 = expf(s1 - m), e2 = expf(s2 - m), e3 = expf(s3 - m);
        float inv = 1.0f / (e0 + e1 + e2 + e3);
        wsm[0] = e0 * inv; wsm[1] = e1 * inv; wsm[2] = e2 * inv; wsm[3] = e3 * inv;
    }
#pragma unroll
    for (int i = 0; i < 4; ++i) {
        const int row = row0 + (ty << 2) + i;
        const int b = row >> 11, l = row & (LQ - 1);
        const int c = l >> 6, t = l & 63;
#pragma unroll
        for (int j = 0; j < 4; ++j) {
            const int p = (tx << 2) + j;
            float u = acc[i][j] + b2[p];
            float ph = tanhf(u) * PI_F;
            float sp, cp;
            sincosf(ph, &sp, &cp);
            const float wg = ISQ ? wsm[p >> 4] : 1.0f;
            const unsigned short cb = f2bf(cp * wg), sb = f2bf(sp * wg);
            FROW[(size_t)row * FF + 2 * p + 0] = cb;
            FROW[(size_t)row * FF + 2 * p + 1] = sb;
            if (!ISQ) {
                const size_t base = ((size_t)(b * NC + c) * FF) * TC;
                FT[base + (size_t)(2 * p + 0) * TC + t] = cb;
                FT[base + (size_t)(2 * p + 1) * TC + t] = sb;
            }
        }
    }
}

// ---------------- pass A: per-chunk state St[b][c][d][f] = sum_t Vt[d][t]*CKt[f][t] ----------------
__global__ __launch_bounds__(256) void passA_mfma(
    const unsigned short* __restrict__ Vt, const unsigned short* __restrict__ CKt,
    float* __restrict__ Stf)
{
    const int tid = threadIdx.x;
    const int w = tid >> 6, lane = tid & 63, grp = lane >> 4, lid = lane & 15;
    const int dq = blockIdx.x, c = blockIdx.y, b = blockIdx.z;
    const int d0 = dq * 128 + w * 32;
    const size_t cb = (size_t)(b * NC + c);
    f32x4 acc[2][8];
#pragma unroll
    for (int md = 0; md < 2; ++md)
#pragma unroll
        for (int nf = 0; nf < 8; ++nf) acc[md][nf] = (f32x4)0.f;
#pragma unroll
    for (int kt = 0; kt < 2; ++kt) {
        bf16x8 av[2], bk[8];
#pragma unroll
        for (int md = 0; md < 2; ++md)
            av[md] = *(const bf16x8*)(Vt + (cb * DD + d0 + md * 16 + lid) * TC + kt * 32 + grp * 8);
#pragma unroll
        for (int nf = 0; nf < 8; ++nf)
            bk[nf] = *(const bf16x8*)(CKt + (cb * FF + nf * 16 + lid) * TC + kt * 32 + grp * 8);
#pragma unroll
        for (int md = 0; md < 2; ++md)
#pragma unroll
            for (int nf = 0; nf < 8; ++nf)
                acc[md][nf] = __builtin_amdgcn_mfma_f32_16x16x32_bf16(av[md], bk[nf], acc[md][nf], 0, 0, 0);
    }
#pragma unroll
    for (int md = 0; md < 2; ++md)
#pragma unroll
        for (int nf = 0; nf < 8; ++nf)
#pragma unroll
            for (int r = 0; r < 4; ++r) {
                const int d = d0 + md * 16 + grp * 4 + r;
                const int f = nf * 16 + lid;
                Stf[(cb * DD + d) * FF + f] = acc[md][nf][r];
            }
}

// ---------------- pass B: exclusive prefix over chunks, emit bf16 state ----------------
__global__ __launch_bounds__(256) void prefix_mfma(
    const float* __restrict__ Stf, unsigned short* __restrict__ Stb)
{
    const int gid = blockIdx.x * 256 + threadIdx.x;  // b*(DD*FF) + d*FF + f
    const int b = gid >> 16;                          // DD*FF = 65536
    const int df = gid & 65535;
    float run = 0.f;
    for (int c = 0; c < NC; ++c) {
        const size_t idx = ((size_t)(b * NC + c) << 16) + df;
        Stb[idx] = f2bf(run);
        run += Stf[idx];
    }
}

// ---------------- pass C: r = tril(CQ CK^T) V + CQ S_prefix ----------------
__global__ __launch_bounds__(128) void passC_mfma(
    const unsigned short* __restrict__ CQb, const unsigned short* __restrict__ CKb,
    const unsigned short* __restrict__ Vt, const unsigned short* __restrict__ Stb,
    float* __restrict__ R)
{
    __shared__ unsigned short P[64][72];
    const int tid = threadIdx.x;
    const int w = tid >> 6, lane = tid & 63, grp = lane >> 4, lid = lane & 15;
    const int dh = blockIdx.x, c = blockIdx.y, b = blockIdx.z;
    const size_t rowbase = (size_t)b * LQ + c * 64;
    const size_t cb = (size_t)(b * NC + c);
    // QK^T: wave w computes rows [32w, 32w+32)
    f32x4 qk[2][4];
#pragma unroll
    for (int mi = 0; mi < 2; ++mi)
#pragma unroll
        for (int nt = 0; nt < 4; ++nt) qk[mi][nt] = (f32x4)0.f;
#pragma unroll
    for (int kf = 0; kf < 4; ++kf) {
        bf16x8 aq[2], bk[4];
#pragma unroll
        for (int mi = 0; mi < 2; ++mi)
            aq[mi] = *(const bf16x8*)(CQb + (rowbase + (2 * w + mi) * 16 + lid) * FF + kf * 32 + grp * 8);
#pragma unroll
        for (int nt = 0; nt < 4; ++nt)
            bk[nt] = *(const bf16x8*)(CKb + (rowbase + nt * 16 + lid) * FF + kf * 32 + grp * 8);
#pragma unroll
        for (int mi = 0; mi < 2; ++mi)
#pragma unroll
            for (int nt = 0; nt < 4; ++nt)
                qk[mi][nt] = __builtin_amdgcn_mfma_f32_16x16x32_bf16(aq[mi], bk[nt], qk[mi][nt], 0, 0, 0);
    }
#pragma unroll
    for (int mi = 0; mi < 2; ++mi)
#pragma unroll
        for (int nt = 0; nt < 4; ++nt)
#pragma unroll
            for (int r = 0; r < 4; ++r) {
                const int row = (2 * w + mi) * 16 + grp * 4 + r;
                const int col = nt * 16 + lid;
                P[row][col] = f2bf(col <= row ? qk[mi][nt][r] : 0.f);
            }
    __syncthreads();
    // output tile: wave w covers d in [dh*128 + 64w, +64)
    const int d0 = dh * 128 + w * 64;
    f32x4 racc[4][4];
#pragma unroll
    for (int ml = 0; ml < 4; ++ml)
#pragma unroll
        for (int nd = 0; nd < 4; ++nd) racc[ml][nd] = (f32x4)0.f;
    // intra-chunk: tril(P) @ V
#pragma unroll
    for (int kt = 0; kt < 2; ++kt) {
        bf16x8 ap[4], bv[4];
#pragma unroll
        for (int ml = 0; ml < 4; ++ml)
            ap[ml] = *(const bf16x8*)&P[ml * 16 + lid][kt * 32 + grp * 8];
#pragma unroll
        for (int nd = 0; nd < 4; ++nd)
            bv[nd] = *(const bf16x8*)(Vt + (cb * DD + d0 + nd * 16 + lid) * TC + kt * 32 + grp * 8);
#pragma unroll
        for (int ml = 0; ml < 4; ++ml)
#pragma unroll
            for (int nd = 0; nd < 4; ++nd)
                racc[ml][nd] = __builtin_amdgcn_mfma_f32_16x16x32_bf16(ap[ml], bv[nd], racc[ml][nd], 0, 0, 0);
    }
    // inter-chunk: CQ @ S_prefix^T
#pragma unroll
    for (int kf = 0; kf < 4; ++kf) {
        bf16x8 aq[4], bs[4];
#pragma unroll
        for (int ml = 0; ml < 4; ++ml)
            aq[ml] = *(const bf16x8*)(CQb + (rowbase + ml * 16 + lid) * FF + kf * 32 + grp * 8);
#pragma unroll
        for (int nd = 0; nd < 4; ++nd)
            bs[nd] = *(const bf16x8*)(Stb + (cb * DD + d0 + nd * 16 + lid) * FF + kf * 32 + grp * 8);
#pragma unroll
        for (int ml = 0; ml < 4; ++ml)
#pragma unroll
            for (int nd = 0; nd < 4; ++nd)
                racc[ml][nd] = __builtin_amdgcn_mfma_f32_16x16x32_bf16(aq[ml], bs[nd], racc[ml][nd], 0, 0, 0);
    }
#pragma unroll
    for (int ml = 0; ml < 4; ++ml)
#pragma unroll
        for (int nd = 0; nd < 4; ++nd)
#pragma unroll
            for (int r = 0; r < 4; ++r) {
                const int l = ml * 16 + grp * 4 + r;
                const int d = d0 + nd * 16 + lid;
                R[(rowbase + l) * DD + d] = racc[ml][nd][r];
            }
}

// ---------------- position norm + LayerNorm ----------------
__global__ __launch_bounds__(256) void ln_kernel(
    const float* __restrict__ R, const float* __restrict__ g,
    const float* __restrict__ be, float* __restrict__ YN)
{
    const int row = blockIdx.x;
    const int l = row & (LQ - 1);
    const int tid = threadIdx.x;
    const float pscale = rsqrtf((float)((l + 1) * PPL));
    float y0 = R[(size_t)row * DD + tid] * pscale;
    float y1 = R[(size_t)row * DD + 256 + tid] * pscale;
    float s = y0 + y1;
    float q = y0 * y0 + y1 * y1;
#pragma unroll
    for (int off = 32; off >= 1; off >>= 1) {
        s += __shfl_xor(s, off, 64);
        q += __shfl_xor(q, off, 64);
    }
    __shared__ float rs[4], rq[4];
    const int wid = tid >> 6, lane = tid & 63;
    if (lane == 0) { rs[wid] = s; rq[wid] = q; }
    __syncthreads();
    const float ts = rs[0] + rs[1] + rs[2] + rs[3];
    const float tq = rq[0] + rq[1] + rq[2] + rq[3];
    const float mu = ts * (1.0f / DD);
    float var = tq * (1.0f / DD) - mu * mu;
    const float rstd = rsqrtf(var + 1e-5f);
    YN[(size_t)row * DD + tid] = (y0 - mu) * rstd * g[tid] + be[tid];
    YN[(size_t)row * DD + 256 + tid] = (y1 - mu) * rstd * g[tid + 256] + be[tid + 256];
}

extern "C" void kernel_launch(void* const* d_in, const int* in_sizes, int n_in,
                              void* d_out, int out_size, void* d_ws, size_t ws_size,
                              hipStream_t stream)
{
    const float* x   = (const float*)d_in[0];
    const float* sw  = (const float*)d_in[1];
    const float* kw1 = (const float*)d_in[2];
    const float* kb1 = (const float*)d_in[3];
    const float* kw2 = (const float*)d_in[4];
    const float* kb2 = (const float*)d_in[5];
    const float* qw1 = (const float*)d_in[6];
    const float* qb1 = (const float*)d_in[7];
    const float* qw2 = (const float*)d_in[8];
    const float* qb2 = (const float*)d_in[9];
    const float* vw  = (const float*)d_in[10];
    const float* vb  = (const float*)d_in[11];
    const float* lng = (const float*)d_in[12];
    const float* lnb = (const float*)d_in[13];
    const float* ow  = (const float*)d_in[14];
    const float* ob  = (const float*)d_in[15];
    float* out = (float*)d_out;

    float* ws = (float*)d_ws;
    const size_t MR = (size_t)NB * LQ;  // 4096 rows
    float* hk  = ws;                           // 2M floats
    float* hq  = hk + MR * DD;                 // 2M
    float* Stf = hq + MR * DD;                 // B*NC*DD*FF = 4M floats
    float* Rb  = Stf + (size_t)NB * NC * DD * FF;  // 2M
    float* YN  = Rb + MR * DD;                 // 2M
    unsigned short* CQb = (unsigned short*)(YN + MR * DD);   // 4096*128 bf16
    unsigned short* CKb = CQb + MR * FF;
    unsigned short* CKt = CKb + MR * FF;
    unsigned short* Vt  = CKt + MR * FF;       // 4096*512 bf16
    unsigned short* Stb = Vt + MR * DD;        // 4M bf16

    const dim3 blk(256);
    const dim3 g1(DD / 64, MR / 64);
    hipLaunchKernelGGL((gemm_kernel<1, 0, 0>), g1, blk, 0, stream, x, kw1, kb1, nullptr, hk, nullptr, (int)MR, DD, DD);
    hipLaunchKernelGGL((gemm_kernel<1, 0, 0>), g1, blk, 0, stream, x, qw1, qb1, nullptr, hq, nullptr, (int)MR, DD, DD);
    hipLaunchKernelGGL((gemm_kernel<0, 0, 1>), g1, blk, 0, stream, x, vw, vb, nullptr, nullptr, Vt, (int)MR, DD, DD);
    const dim3 gp(MR / 64);
    hipLaunchKernelGGL((phase_kernel<0>), gp, blk, 0, stream, hk, kw2, kb2, nullptr, CKb, CKt, (int)MR, DD);
    hipLaunchKernelGGL((phase_kernel<1>), gp, blk, 0, stream, hq, qw2, qb2, sw, CQb, nullptr, (int)MR, DD);
    hipLaunchKernelGGL(passA_mfma, dim3(4, NC, NB), blk, 0, stream, Vt, CKt, Stf);
    hipLaunchKernelGGL(prefix_mfma, dim3((NB * DD * FF) / 256), blk, 0, stream, Stf, Stb);
    hipLaunchKernelGGL(passC_mfma, dim3(4, NC, NB), dim3(128), 0, stream, CQb, CKb, Vt, Stb, Rb);
    hipLaunchKernelGGL(ln_kernel, dim3((unsigned)MR), blk, 0, stream, Rb, lng, lnb, YN);
    hipLaunchKernelGGL((gemm_kernel<0, 1, 0>), g1, blk, 0, stream, YN, ow, ob, x, out, nullptr, (int)MR, DD, DD);
}

// Round 4
// 202.861 us; speedup vs baseline: 2.6966x; 1.5689x over previous
//
#include <hip/hip_runtime.h>
#include <math.h>

// Problem constants
constexpr int NB = 2;        // batch
constexpr int LQ = 2048;     // sequence length
constexpr int DD = 512;      // model dim
constexpr int PPL = 16;      // planes per set
constexpr int TPP = 64;      // total planes (S*P)
constexpr int FF = 128;      // feature dim = 2*TPP (cos,sin interleaved)
constexpr int NC = 32;       // chunks
constexpr int TC = 64;       // chunk length
constexpr float PI_F = 3.14159265358979323846f;

typedef __attribute__((ext_vector_type(4))) float f32x4;
typedef __attribute__((ext_vector_type(8))) short bf16x8;

static __device__ __forceinline__ unsigned short f2bf(float x) {
    union { float f; unsigned u; } v; v.f = x;
    unsigned r = v.u + 0x7fff + ((v.u >> 16) & 1);
    return (unsigned short)(r >> 16);
}

// ---------------- cast f32 -> bf16 (vectorized) ----------------
__global__ __launch_bounds__(256) void cast_bf16(
    const float* __restrict__ x, unsigned short* __restrict__ o, int n)
{
    const int i = (blockIdx.x * 256 + threadIdx.x) * 8;
    if (i >= n) return;
    float4 a = *(const float4*)(x + i);
    float4 b = *(const float4*)(x + i + 4);
    ushort4 u0 = {f2bf(a.x), f2bf(a.y), f2bf(a.z), f2bf(a.w)};
    ushort4 u1 = {f2bf(b.x), f2bf(b.y), f2bf(b.z), f2bf(b.w)};
    *(ushort4*)(o + i) = u0;
    *(ushort4*)(o + i + 4) = u1;
}

// ---------------- weight transpose+cast: W[K][N] f32 -> Wt[N][K] bf16 ----------------
// blockIdx.z selects among up to 4 matrices.
__global__ __launch_bounds__(256) void wtrans_kernel(
    const float* __restrict__ w0, const float* __restrict__ w1,
    const float* __restrict__ w2, const float* __restrict__ w3,
    unsigned short* __restrict__ o0, unsigned short* __restrict__ o1,
    unsigned short* __restrict__ o2, unsigned short* __restrict__ o3,
    int K, int N)
{
    const float* W = (blockIdx.z == 0) ? w0 : (blockIdx.z == 1) ? w1 : (blockIdx.z == 2) ? w2 : w3;
    unsigned short* O = (blockIdx.z == 0) ? o0 : (blockIdx.z == 1) ? o1 : (blockIdx.z == 2) ? o2 : o3;
    __shared__ float t[32][33];
    const int tx = threadIdx.x & 31, ty = threadIdx.x >> 5;  // 32x8
    const int n0 = blockIdx.x * 32, k0 = blockIdx.y * 32;
#pragma unroll
    for (int i = 0; i < 4; ++i)
        t[ty + 8 * i][tx] = W[(size_t)(k0 + ty + 8 * i) * N + n0 + tx];
    __syncthreads();
#pragma unroll
    for (int i = 0; i < 4; ++i)
        O[(size_t)(n0 + ty + 8 * i) * K + k0 + tx] = f2bf(t[tx][ty + 8 * i]);
}

// ---------------- bf16 MFMA GEMM: BM=128, BN=64, BK=64, 256 thr (4 waves, wave=64x32) ----------------
// A [M][K] bf16 (k-contig), Bt [N][K] bf16 (k-contig).
// EPI=0: obf[row][col] = bf16(gelu(acc+bias))
// EPI=1: Vt[b][c][col][t] = bf16(acc+bias)   (chunk-transposed value tensor)
// EPI=2: of32[row][col] = acc + bias + resid[row][col]
template<int EPI>
__global__ __launch_bounds__(256) void mgemm(
    const unsigned short* __restrict__ A, const unsigned short* __restrict__ Bt,
    const float* __restrict__ bias, const float* __restrict__ resid,
    unsigned short* __restrict__ obf, float* __restrict__ of32,
    int M, int N, int K)
{
    __shared__ unsigned short As[128 * 72];
    __shared__ unsigned short Bs[64 * 72];
    const int tid = threadIdx.x;
    const int w = tid >> 6, lane = tid & 63, grp = lane >> 4, lid = lane & 15;
    const int wr = w >> 1, wc = w & 1;   // wave tile: rows wr*64, cols wc*32
    const int row0 = blockIdx.y * 128, col0 = blockIdx.x * 64;
    f32x4 acc[4][2];
#pragma unroll
    for (int m = 0; m < 4; ++m)
#pragma unroll
        for (int n = 0; n < 2; ++n) acc[m][n] = (f32x4)0.f;

    for (int k0 = 0; k0 < K; k0 += 64) {
        bf16x8 va[4], vb[2];
#pragma unroll
        for (int i = 0; i < 4; ++i) {
            const int c = tid + i * 256;          // 1024 chunks: row=c>>3, kb=c&7
            va[i] = *(const bf16x8*)(A + (size_t)(row0 + (c >> 3)) * K + k0 + (c & 7) * 8);
        }
#pragma unroll
        for (int i = 0; i < 2; ++i) {
            const int c = tid + i * 256;          // 512 chunks
            vb[i] = *(const bf16x8*)(Bt + (size_t)(col0 + (c >> 3)) * K + k0 + (c & 7) * 8);
        }
        __syncthreads();
#pragma unroll
        for (int i = 0; i < 4; ++i) {
            const int c = tid + i * 256;
            *(bf16x8*)(As + (c >> 3) * 72 + (c & 7) * 8) = va[i];
        }
#pragma unroll
        for (int i = 0; i < 2; ++i) {
            const int c = tid + i * 256;
            *(bf16x8*)(Bs + (c >> 3) * 72 + (c & 7) * 8) = vb[i];
        }
        __syncthreads();
#pragma unroll
        for (int kk = 0; kk < 2; ++kk) {
            bf16x8 af[4], bfr[2];
#pragma unroll
            for (int m = 0; m < 4; ++m)
                af[m] = *(const bf16x8*)(As + (wr * 64 + m * 16 + lid) * 72 + kk * 32 + grp * 8);
#pragma unroll
            for (int n = 0; n < 2; ++n)
                bfr[n] = *(const bf16x8*)(Bs + (wc * 32 + n * 16 + lid) * 72 + kk * 32 + grp * 8);
#pragma unroll
            for (int m = 0; m < 4; ++m)
#pragma unroll
                for (int n = 0; n < 2; ++n)
                    acc[m][n] = __builtin_amdgcn_mfma_f32_16x16x32_bf16(af[m], bfr[n], acc[m][n], 0, 0, 0);
        }
    }
#pragma unroll
    for (int m = 0; m < 4; ++m) {
#pragma unroll
        for (int n = 0; n < 2; ++n) {
            const int col = col0 + wc * 32 + n * 16 + lid;
            const float bc = bias[col];
            if (EPI == 1) {
                const int rowb = row0 + wr * 64 + m * 16 + grp * 4;
                const int b = rowb >> 11, l = rowb & (LQ - 1);
                const int c = l >> 6, t0 = l & 63;
                ushort4 u;
                u.x = f2bf(acc[m][n][0] + bc);
                u.y = f2bf(acc[m][n][1] + bc);
                u.z = f2bf(acc[m][n][2] + bc);
                u.w = f2bf(acc[m][n][3] + bc);
                *(ushort4*)(obf + ((size_t)((b * NC + c) * DD) + col) * TC + t0) = u;
            } else {
#pragma unroll
                for (int r = 0; r < 4; ++r) {
                    const int row = row0 + wr * 64 + m * 16 + grp * 4 + r;
                    float v = acc[m][n][r] + bc;
                    if (EPI == 0) {
                        v = 0.5f * v * (1.0f + erff(v * 0.70710678118654752f));
                        obf[(size_t)row * N + col] = f2bf(v);
                    } else {
                        of32[(size_t)row * N + col] = v + resid[(size_t)row * N + col];
                    }
                }
            }
        }
    }
}

// ---------------- phase GEMM (MFMA): tanh(H@W2+b2)*pi -> cos/sin bf16 features ----------------
// H [M][512] bf16, W2t [64][512] bf16. BM=128, N=64. 4 waves, wave = 32 rows x 64 cols.
// ISQ=0 (K): write CKb[row][f] and CKt[b][c][f][t].  ISQ=1 (Q): CQb[row][f] with softmax(sw).
template<int ISQ>
__global__ __launch_bounds__(256) void phase_mfma(
    const unsigned short* __restrict__ A, const unsigned short* __restrict__ Bt,
    const float* __restrict__ b2, const float* __restrict__ sw,
    unsigned short* __restrict__ FROW, unsigned short* __restrict__ FT)
{
    __shared__ unsigned short As[128 * 72];
    __shared__ unsigned short Bs[64 * 72];
    const int tid = threadIdx.x;
    const int w = tid >> 6, lane = tid & 63, grp = lane >> 4, lid = lane & 15;
    const int row0 = blockIdx.x * 128;
    const int K = DD;
    f32x4 acc[2][4];
#pragma unroll
    for (int m = 0; m < 2; ++m)
#pragma unroll
        for (int n = 0; n < 4; ++n) acc[m][n] = (f32x4)0.f;

    for (int k0 = 0; k0 < K; k0 += 64) {
        bf16x8 va[4], vb[2];
#pragma unroll
        for (int i = 0; i < 4; ++i) {
            const int c = tid + i * 256;
            va[i] = *(const bf16x8*)(A + (size_t)(row0 + (c >> 3)) * K + k0 + (c & 7) * 8);
        }
#pragma unroll
        for (int i = 0; i < 2; ++i) {
            const int c = tid + i * 256;
            vb[i] = *(const bf16x8*)(Bt + (size_t)(c >> 3) * K + k0 + (c & 7) * 8);
        }
        __syncthreads();
#pragma unroll
        for (int i = 0; i < 4; ++i) {
            const int c = tid + i * 256;
            *(bf16x8*)(As + (c >> 3) * 72 + (c & 7) * 8) = va[i];
        }
#pragma unroll
        for (int i = 0; i < 2; ++i) {
            const int c = tid + i * 256;
            *(bf16x8*)(Bs + (c >> 3) * 72 + (c & 7) * 8) = vb[i];
        }
        __syncthreads();
#pragma unroll
        for (int kk = 0; kk < 2; ++kk) {
            bf16x8 af[2], bfr[4];
#pragma unroll
            for (int m = 0; m < 2; ++m)
                af[m] = *(const bf16x8*)(As + (w * 32 + m * 16 + lid) * 72 + kk * 32 + grp * 8);
#pragma unroll
            for (int n = 0; n < 4; ++n)
                bfr[n] = *(const bf16x8*)(Bs + (n * 16 + lid) * 72 + kk * 32 + grp * 8);
#pragma unroll
            for (int m = 0; m < 2; ++m)
#pragma unroll
                for (int n = 0; n < 4; ++n)
                    acc[m][n] = __builtin_amdgcn_mfma_f32_16x16x32_bf16(af[m], bfr[n], acc[m][n], 0, 0, 0);
        }
    }
    float wsm[4] = {1.f, 1.f, 1.f, 1.f};
    if (ISQ) {
        float s0 = sw[0], s1 = sw[1], s2 = sw[2], s3 = sw[3];
        float mx = fmaxf(fmaxf(s0, s1), fmaxf(s2, s3));
        float e0 = expf(s0 - mx), e1 = expf(s1 - mx), e2 = expf(s2 - mx), e3 = expf(s3 - mx);
        float inv = 1.0f / (e0 + e1 + e2 + e3);
        wsm[0] = e0 * inv; wsm[1] = e1 * inv; wsm[2] = e2 * inv; wsm[3] = e3 * inv;
    }
#pragma unroll
    for (int m = 0; m < 2; ++m) {
#pragma unroll
        for (int n = 0; n < 4; ++n) {
            const int p = n * 16 + lid;
            const float bc = b2[p];
            const float wg = ISQ ? wsm[p >> 4] : 1.0f;
#pragma unroll
            for (int r = 0; r < 4; ++r) {
                const int row = row0 + w * 32 + m * 16 + grp * 4 + r;
                float u = acc[m][n][r] + bc;
                float ph = tanhf(u) * PI_F;
                float sp, cp;
                sincosf(ph, &sp, &cp);
                const unsigned short cb = f2bf(cp * wg), sb = f2bf(sp * wg);
                FROW[(size_t)row * FF + 2 * p + 0] = cb;
                FROW[(size_t)row * FF + 2 * p + 1] = sb;
                if (!ISQ) {
                    const int b = row >> 11, l = row & (LQ - 1);
                    const int c = l >> 6, t = l & 63;
                    const size_t base = ((size_t)(b * NC + c) * FF) * TC;
                    FT[base + (size_t)(2 * p + 0) * TC + t] = cb;
                    FT[base + (size_t)(2 * p + 1) * TC + t] = sb;
                }
            }
        }
    }
}

// ---------------- pass A: per-chunk state St[b][c][d][f] = sum_t Vt[d][t]*CKt[f][t] ----------------
__global__ __launch_bounds__(256) void passA_mfma(
    const unsigned short* __restrict__ Vt, const unsigned short* __restrict__ CKt,
    float* __restrict__ Stf)
{
    const int tid = threadIdx.x;
    const int w = tid >> 6, lane = tid & 63, grp = lane >> 4, lid = lane & 15;
    const int dq = blockIdx.x, c = blockIdx.y, b = blockIdx.z;
    const int d0 = dq * 128 + w * 32;
    const size_t cb = (size_t)(b * NC + c);
    f32x4 acc[2][8];
#pragma unroll
    for (int md = 0; md < 2; ++md)
#pragma unroll
        for (int nf = 0; nf < 8; ++nf) acc[md][nf] = (f32x4)0.f;
#pragma unroll
    for (int kt = 0; kt < 2; ++kt) {
        bf16x8 av[2], bk[8];
#pragma unroll
        for (int md = 0; md < 2; ++md)
            av[md] = *(const bf16x8*)(Vt + (cb * DD + d0 + md * 16 + lid) * TC + kt * 32 + grp * 8);
#pragma unroll
        for (int nf = 0; nf < 8; ++nf)
            bk[nf] = *(const bf16x8*)(CKt + (cb * FF + nf * 16 + lid) * TC + kt * 32 + grp * 8);
#pragma unroll
        for (int md = 0; md < 2; ++md)
#pragma unroll
            for (int nf = 0; nf < 8; ++nf)
                acc[md][nf] = __builtin_amdgcn_mfma_f32_16x16x32_bf16(av[md], bk[nf], acc[md][nf], 0, 0, 0);
    }
#pragma unroll
    for (int md = 0; md < 2; ++md)
#pragma unroll
        for (int nf = 0; nf < 8; ++nf)
#pragma unroll
            for (int r = 0; r < 4; ++r) {
                const int d = d0 + md * 16 + grp * 4 + r;
                const int f = nf * 16 + lid;
                Stf[(cb * DD + d) * FF + f] = acc[md][nf][r];
            }
}

// ---------------- pass B: exclusive prefix over chunks, emit bf16 state ----------------
__global__ __launch_bounds__(256) void prefix_mfma(
    const float* __restrict__ Stf, unsigned short* __restrict__ Stb)
{
    const int gid = blockIdx.x * 256 + threadIdx.x;  // b*(DD*FF) + d*FF + f
    const int b = gid >> 16;                          // DD*FF = 65536
    const int df = gid & 65535;
    float run = 0.f;
    for (int c = 0; c < NC; ++c) {
        const size_t idx = ((size_t)(b * NC + c) << 16) + df;
        Stb[idx] = f2bf(run);
        run += Stf[idx];
    }
}

// ---------------- pass C: r = tril(CQ CK^T) V + CQ S_prefix ----------------
__global__ __launch_bounds__(128) void passC_mfma(
    const unsigned short* __restrict__ CQb, const unsigned short* __restrict__ CKb,
    const unsigned short* __restrict__ Vt, const unsigned short* __restrict__ Stb,
    float* __restrict__ R)
{
    __shared__ unsigned short P[64][72];
    const int tid = threadIdx.x;
    const int w = tid >> 6, lane = tid & 63, grp = lane >> 4, lid = lane & 15;
    const int dh = blockIdx.x, c = blockIdx.y, b = blockIdx.z;
    const size_t rowbase = (size_t)b * LQ + c * 64;
    const size_t cb = (size_t)(b * NC + c);
    f32x4 qk[2][4];
#pragma unroll
    for (int mi = 0; mi < 2; ++mi)
#pragma unroll
        for (int nt = 0; nt < 4; ++nt) qk[mi][nt] = (f32x4)0.f;
#pragma unroll
    for (int kf = 0; kf < 4; ++kf) {
        bf16x8 aq[2], bk[4];
#pragma unroll
        for (int mi = 0; mi < 2; ++mi)
            aq[mi] = *(const bf16x8*)(CQb + (rowbase + (2 * w + mi) * 16 + lid) * FF + kf * 32 + grp * 8);
#pragma unroll
        for (int nt = 0; nt < 4; ++nt)
            bk[nt] = *(const bf16x8*)(CKb + (rowbase + nt * 16 + lid) * FF + kf * 32 + grp * 8);
#pragma unroll
        for (int mi = 0; mi < 2; ++mi)
#pragma unroll
            for (int nt = 0; nt < 4; ++nt)
                qk[mi][nt] = __builtin_amdgcn_mfma_f32_16x16x32_bf16(aq[mi], bk[nt], qk[mi][nt], 0, 0, 0);
    }
#pragma unroll
    for (int mi = 0; mi < 2; ++mi)
#pragma unroll
        for (int nt = 0; nt < 4; ++nt)
#pragma unroll
            for (int r = 0; r < 4; ++r) {
                const int row = (2 * w + mi) * 16 + grp * 4 + r;
                const int col = nt * 16 + lid;
                P[row][col] = f2bf(col <= row ? qk[mi][nt][r] : 0.f);
            }
    __syncthreads();
    const int d0 = dh * 128 + w * 64;
    f32x4 racc[4][4];
#pragma unroll
    for (int ml = 0; ml < 4; ++ml)
#pragma unroll
        for (int nd = 0; nd < 4; ++nd) racc[ml][nd] = (f32x4)0.f;
#pragma unroll
    for (int kt = 0; kt < 2; ++kt) {
        bf16x8 ap[4], bv[4];
#pragma unroll
        for (int ml = 0; ml < 4; ++ml)
            ap[ml] = *(const bf16x8*)&P[ml * 16 + lid][kt * 32 + grp * 8];
#pragma unroll
        for (int nd = 0; nd < 4; ++nd)
            bv[nd] = *(const bf16x8*)(Vt + (cb * DD + d0 + nd * 16 + lid) * TC + kt * 32 + grp * 8);
#pragma unroll
        for (int ml = 0; ml < 4; ++ml)
#pragma unroll
            for (int nd = 0; nd < 4; ++nd)
                racc[ml][nd] = __builtin_amdgcn_mfma_f32_16x16x32_bf16(ap[ml], bv[nd], racc[ml][nd], 0, 0, 0);
    }
#pragma unroll
    for (int kf = 0; kf < 4; ++kf) {
        bf16x8 aq[4], bs[4];
#pragma unroll
        for (int ml = 0; ml < 4; ++ml)
            aq[ml] = *(const bf16x8*)(CQb + (rowbase + ml * 16 + lid) * FF + kf * 32 + grp * 8);
#pragma unroll
        for (int nd = 0; nd < 4; ++nd)
            bs[nd] = *(const bf16x8*)(Stb + (cb * DD + d0 + nd * 16 + lid) * FF + kf * 32 + grp * 8);
#pragma unroll
        for (int ml = 0; ml < 4; ++ml)
#pragma unroll
            for (int nd = 0; nd < 4; ++nd)
                racc[ml][nd] = __builtin_amdgcn_mfma_f32_16x16x32_bf16(aq[ml], bs[nd], racc[ml][nd], 0, 0, 0);
    }
#pragma unroll
    for (int ml = 0; ml < 4; ++ml)
#pragma unroll
        for (int nd = 0; nd < 4; ++nd)
#pragma unroll
            for (int r = 0; r < 4; ++r) {
                const int l = ml * 16 + grp * 4 + r;
                const int d = d0 + nd * 16 + lid;
                R[(rowbase + l) * DD + d] = racc[ml][nd][r];
            }
}

// ---------------- position norm + LayerNorm (bf16 out) ----------------
__global__ __launch_bounds__(256) void ln_kernel(
    const float* __restrict__ R, const float* __restrict__ g,
    const float* __restrict__ be, unsigned short* __restrict__ YN)
{
    const int row = blockIdx.x;
    const int l = row & (LQ - 1);
    const int tid = threadIdx.x;
    const float pscale = rsqrtf((float)((l + 1) * PPL));
    float y0 = R[(size_t)row * DD + tid] * pscale;
    float y1 = R[(size_t)row * DD + 256 + tid] * pscale;
    float s = y0 + y1;
    float q = y0 * y0 + y1 * y1;
#pragma unroll
    for (int off = 32; off >= 1; off >>= 1) {
        s += __shfl_xor(s, off, 64);
        q += __shfl_xor(q, off, 64);
    }
    __shared__ float rs[4], rq[4];
    const int wid = tid >> 6, lane = tid & 63;
    if (lane == 0) { rs[wid] = s; rq[wid] = q; }
    __syncthreads();
    const float ts = rs[0] + rs[1] + rs[2] + rs[3];
    const float tq = rq[0] + rq[1] + rq[2] + rq[3];
    const float mu = ts * (1.0f / DD);
    float var = tq * (1.0f / DD) - mu * mu;
    const float rstd = rsqrtf(var + 1e-5f);
    YN[(size_t)row * DD + tid] = f2bf((y0 - mu) * rstd * g[tid] + be[tid]);
    YN[(size_t)row * DD + 256 + tid] = f2bf((y1 - mu) * rstd * g[tid + 256] + be[tid + 256]);
}

extern "C" void kernel_launch(void* const* d_in, const int* in_sizes, int n_in,
                              void* d_out, int out_size, void* d_ws, size_t ws_size,
                              hipStream_t stream)
{
    const float* x   = (const float*)d_in[0];
    const float* sw  = (const float*)d_in[1];
    const float* kw1 = (const float*)d_in[2];
    const float* kb1 = (const float*)d_in[3];
    const float* kw2 = (const float*)d_in[4];
    const float* kb2 = (const float*)d_in[5];
    const float* qw1 = (const float*)d_in[6];
    const float* qb1 = (const float*)d_in[7];
    const float* qw2 = (const float*)d_in[8];
    const float* qb2 = (const float*)d_in[9];
    const float* vw  = (const float*)d_in[10];
    const float* vb  = (const float*)d_in[11];
    const float* lng = (const float*)d_in[12];
    const float* lnb = (const float*)d_in[13];
    const float* ow  = (const float*)d_in[14];
    const float* ob  = (const float*)d_in[15];
    float* out = (float*)d_out;

    const size_t MR = (size_t)NB * LQ;  // 4096 rows
    float* ws = (float*)d_ws;
    float* Stf = ws;                                  // NB*NC*DD*FF f32 = 4M
    float* Rb  = Stf + (size_t)NB * NC * DD * FF;     // 2M f32
    unsigned short* xb   = (unsigned short*)(Rb + MR * DD);
    unsigned short* hkb  = xb + MR * DD;
    unsigned short* hqb  = hkb + MR * DD;
    unsigned short* YNb  = hqb + MR * DD;
    unsigned short* Vt   = YNb + MR * DD;
    unsigned short* CQb  = Vt + MR * DD;
    unsigned short* CKb  = CQb + MR * FF;
    unsigned short* CKt  = CKb + MR * FF;
    unsigned short* Stb  = CKt + MR * FF;             // 4M shorts
    unsigned short* kw1t = Stb + (size_t)NB * NC * DD * FF;
    unsigned short* qw1t = kw1t + (size_t)DD * DD;
    unsigned short* vwt  = qw1t + (size_t)DD * DD;
    unsigned short* owt  = vwt + (size_t)DD * DD;
    unsigned short* kw2t = owt + (size_t)DD * DD;
    unsigned short* qw2t = kw2t + (size_t)TPP * DD;

    const dim3 blk(256);
    hipLaunchKernelGGL(cast_bf16, dim3((unsigned)(MR * DD / 2048)), blk, 0, stream, x, xb, (int)(MR * DD));
    hipLaunchKernelGGL(wtrans_kernel, dim3(16, 16, 4), blk, 0, stream,
                       kw1, qw1, vw, ow, kw1t, qw1t, vwt, owt, DD, DD);
    hipLaunchKernelGGL(wtrans_kernel, dim3(2, 16, 2), blk, 0, stream,
                       kw2, qw2, kw2, qw2, kw2t, qw2t, kw2t, qw2t, DD, TPP);

    const dim3 gg(DD / 64, MR / 128);
    hipLaunchKernelGGL((mgemm<0>), gg, blk, 0, stream, xb, kw1t, kb1, nullptr, hkb, nullptr, (int)MR, DD, DD);
    hipLaunchKernelGGL((mgemm<0>), gg, blk, 0, stream, xb, qw1t, qb1, nullptr, hqb, nullptr, (int)MR, DD, DD);
    hipLaunchKernelGGL((mgemm<1>), gg, blk, 0, stream, xb, vwt, vb, nullptr, Vt, nullptr, (int)MR, DD, DD);

    const dim3 gp(MR / 128);
    hipLaunchKernelGGL((phase_mfma<0>), gp, blk, 0, stream, hkb, kw2t, kb2, nullptr, CKb, CKt);
    hipLaunchKernelGGL((phase_mfma<1>), gp, blk, 0, stream, hqb, qw2t, qb2, sw, CQb, nullptr);

    hipLaunchKernelGGL(passA_mfma, dim3(4, NC, NB), blk, 0, stream, Vt, CKt, Stf);
    hipLaunchKernelGGL(prefix_mfma, dim3((NB * DD * FF) / 256), blk, 0, stream, Stf, Stb);
    hipLaunchKernelGGL(passC_mfma, dim3(4, NC, NB), dim3(128), 0, stream, CQb, CKb, Vt, Stb, Rb);
    hipLaunchKernelGGL(ln_kernel, dim3((unsigned)MR), blk, 0, stream, Rb, lng, lnb, YNb);
    hipLaunchKernelGGL((mgemm<2>), gg, blk, 0, stream, YNb, owt, ob, x, nullptr, out, (int)MR, DD, DD);
}

// Round 5
// 154.212 us; speedup vs baseline: 3.5473x; 1.3155x over previous
//
#include <hip/hip_runtime.h>
#include <math.h>

// Problem constants
constexpr int NB = 2;        // batch
constexpr int LQ = 2048;     // sequence length
constexpr int DD = 512;      // model dim
constexpr int PPL = 16;      // planes per set
constexpr int TPP = 64;      // total planes (S*P)
constexpr int FF = 128;      // feature dim = 2*TPP (cos,sin interleaved)
constexpr int NC = 32;       // chunks
constexpr int TC = 64;       // chunk length
constexpr float PI_F = 3.14159265358979323846f;

typedef __attribute__((ext_vector_type(4))) float f32x4;
typedef __attribute__((ext_vector_type(8))) short bf16x8;

static __device__ __forceinline__ unsigned short f2bf(float x) {
    union { float f; unsigned u; } v; v.f = x;
    unsigned r = v.u + 0x7fff + ((v.u >> 16) & 1);
    return (unsigned short)(r >> 16);
}
static __device__ __forceinline__ float bf2f(unsigned short u) {
    union { unsigned u; float f; } v; v.u = ((unsigned)u) << 16;
    return v.f;
}

// ---------------- cast f32 -> bf16 (vectorized) ----------------
__global__ __launch_bounds__(256) void cast_bf16(
    const float* __restrict__ x, unsigned short* __restrict__ o, int n)
{
    const int i = (blockIdx.x * 256 + threadIdx.x) * 8;
    if (i >= n) return;
    float4 a = *(const float4*)(x + i);
    float4 b = *(const float4*)(x + i + 4);
    ushort4 u0 = {f2bf(a.x), f2bf(a.y), f2bf(a.z), f2bf(a.w)};
    ushort4 u1 = {f2bf(b.x), f2bf(b.y), f2bf(b.z), f2bf(b.w)};
    *(ushort4*)(o + i) = u0;
    *(ushort4*)(o + i + 4) = u1;
}

// ---------------- weight transpose+cast: W[K][N] f32 -> Wt[N][K] bf16 ----------------
__global__ __launch_bounds__(256) void wtrans_kernel(
    const float* __restrict__ w0, const float* __restrict__ w1,
    const float* __restrict__ w2, const float* __restrict__ w3,
    unsigned short* __restrict__ o0, unsigned short* __restrict__ o1,
    unsigned short* __restrict__ o2, unsigned short* __restrict__ o3,
    int K, int N)
{
    const float* W = (blockIdx.z == 0) ? w0 : (blockIdx.z == 1) ? w1 : (blockIdx.z == 2) ? w2 : w3;
    unsigned short* O = (blockIdx.z == 0) ? o0 : (blockIdx.z == 1) ? o1 : (blockIdx.z == 2) ? o2 : o3;
    __shared__ float t[32][33];
    const int tx = threadIdx.x & 31, ty = threadIdx.x >> 5;  // 32x8
    const int n0 = blockIdx.x * 32, k0 = blockIdx.y * 32;
#pragma unroll
    for (int i = 0; i < 4; ++i)
        t[ty + 8 * i][tx] = W[(size_t)(k0 + ty + 8 * i) * N + n0 + tx];
    __syncthreads();
#pragma unroll
    for (int i = 0; i < 4; ++i)
        O[(size_t)(n0 + ty + 8 * i) * K + k0 + tx] = f2bf(t[tx][ty + 8 * i]);
}

// ---------------- fused x-GEMMs: z=0 -> gelu->hkb, z=1 -> gelu->hqb, z=2 -> Vt ----------------
// BM=128, BN=64, BK=64, 256 thr (4 waves, wave tile 64x32). A,Bt k-contiguous bf16.
__global__ __launch_bounds__(256) void mgemm_fused(
    const unsigned short* __restrict__ A,
    const unsigned short* __restrict__ kw1t, const unsigned short* __restrict__ qw1t,
    const unsigned short* __restrict__ vwt,
    const float* __restrict__ kb1, const float* __restrict__ qb1, const float* __restrict__ vb,
    unsigned short* __restrict__ hkb, unsigned short* __restrict__ hqb,
    unsigned short* __restrict__ Vt)
{
    const int z = blockIdx.z;
    const unsigned short* Bt = (z == 0) ? kw1t : (z == 1) ? qw1t : vwt;
    const float* bias = (z == 0) ? kb1 : (z == 1) ? qb1 : vb;
    unsigned short* obf = (z == 0) ? hkb : (z == 1) ? hqb : Vt;
    const int K = DD, N = DD;

    __shared__ unsigned short As[128 * 72];
    __shared__ unsigned short Bs[64 * 72];
    const int tid = threadIdx.x;
    const int w = tid >> 6, lane = tid & 63, grp = lane >> 4, lid = lane & 15;
    const int wr = w >> 1, wc = w & 1;
    const int row0 = blockIdx.y * 128, col0 = blockIdx.x * 64;
    f32x4 acc[4][2];
#pragma unroll
    for (int m = 0; m < 4; ++m)
#pragma unroll
        for (int n = 0; n < 2; ++n) acc[m][n] = (f32x4)0.f;

    for (int k0 = 0; k0 < K; k0 += 64) {
        bf16x8 va[4], vbv[2];
#pragma unroll
        for (int i = 0; i < 4; ++i) {
            const int c = tid + i * 256;
            va[i] = *(const bf16x8*)(A + (size_t)(row0 + (c >> 3)) * K + k0 + (c & 7) * 8);
        }
#pragma unroll
        for (int i = 0; i < 2; ++i) {
            const int c = tid + i * 256;
            vbv[i] = *(const bf16x8*)(Bt + (size_t)(col0 + (c >> 3)) * K + k0 + (c & 7) * 8);
        }
        __syncthreads();
#pragma unroll
        for (int i = 0; i < 4; ++i) {
            const int c = tid + i * 256;
            *(bf16x8*)(As + (c >> 3) * 72 + (c & 7) * 8) = va[i];
        }
#pragma unroll
        for (int i = 0; i < 2; ++i) {
            const int c = tid + i * 256;
            *(bf16x8*)(Bs + (c >> 3) * 72 + (c & 7) * 8) = vbv[i];
        }
        __syncthreads();
#pragma unroll
        for (int kk = 0; kk < 2; ++kk) {
            bf16x8 af[4], bfr[2];
#pragma unroll
            for (int m = 0; m < 4; ++m)
                af[m] = *(const bf16x8*)(As + (wr * 64 + m * 16 + lid) * 72 + kk * 32 + grp * 8);
#pragma unroll
            for (int n = 0; n < 2; ++n)
                bfr[n] = *(const bf16x8*)(Bs + (wc * 32 + n * 16 + lid) * 72 + kk * 32 + grp * 8);
#pragma unroll
            for (int m = 0; m < 4; ++m)
#pragma unroll
                for (int n = 0; n < 2; ++n)
                    acc[m][n] = __builtin_amdgcn_mfma_f32_16x16x32_bf16(af[m], bfr[n], acc[m][n], 0, 0, 0);
        }
    }
#pragma unroll
    for (int m = 0; m < 4; ++m) {
#pragma unroll
        for (int n = 0; n < 2; ++n) {
            const int col = col0 + wc * 32 + n * 16 + lid;
            const float bc = bias[col];
            if (z == 2) {
                const int rowb = row0 + wr * 64 + m * 16 + grp * 4;
                const int b = rowb >> 11, l = rowb & (LQ - 1);
                const int c = l >> 6, t0 = l & 63;
                ushort4 u;
                u.x = f2bf(acc[m][n][0] + bc);
                u.y = f2bf(acc[m][n][1] + bc);
                u.z = f2bf(acc[m][n][2] + bc);
                u.w = f2bf(acc[m][n][3] + bc);
                *(ushort4*)(Vt + ((size_t)((b * NC + c) * DD) + col) * TC + t0) = u;
            } else {
#pragma unroll
                for (int r = 0; r < 4; ++r) {
                    const int row = row0 + wr * 64 + m * 16 + grp * 4 + r;
                    float v = acc[m][n][r] + bc;
                    v = 0.5f * v * (1.0f + erff(v * 0.70710678118654752f));
                    obf[(size_t)row * N + col] = f2bf(v);
                }
            }
        }
    }
}

// ---------------- fused phase GEMM: y=0 -> K features, y=1 -> Q features ----------------
// BM=64, N=64, K=512. 4 waves, wave tile 16 rows x 64 cols.
__global__ __launch_bounds__(256) void phase_fused(
    const unsigned short* __restrict__ hkb, const unsigned short* __restrict__ hqb,
    const unsigned short* __restrict__ kw2t, const unsigned short* __restrict__ qw2t,
    const float* __restrict__ kb2, const float* __restrict__ qb2,
    const float* __restrict__ sw,
    unsigned short* __restrict__ CKb, unsigned short* __restrict__ CQb,
    unsigned short* __restrict__ CKt)
{
    const int isq = blockIdx.y;
    const unsigned short* A = isq ? hqb : hkb;
    const unsigned short* Bt = isq ? qw2t : kw2t;
    const float* b2 = isq ? qb2 : kb2;
    unsigned short* FROW = isq ? CQb : CKb;
    const int K = DD;

    __shared__ unsigned short As[64 * 72];
    __shared__ unsigned short Bs[64 * 72];
    const int tid = threadIdx.x;
    const int w = tid >> 6, lane = tid & 63, grp = lane >> 4, lid = lane & 15;
    const int row0 = blockIdx.x * 64;
    f32x4 acc[4];
#pragma unroll
    for (int n = 0; n < 4; ++n) acc[n] = (f32x4)0.f;

    for (int k0 = 0; k0 < K; k0 += 64) {
        bf16x8 va[2], vbv[2];
#pragma unroll
        for (int i = 0; i < 2; ++i) {
            const int c = tid + i * 256;
            va[i] = *(const bf16x8*)(A + (size_t)(row0 + (c >> 3)) * K + k0 + (c & 7) * 8);
            vbv[i] = *(const bf16x8*)(Bt + (size_t)(c >> 3) * K + k0 + (c & 7) * 8);
        }
        __syncthreads();
#pragma unroll
        for (int i = 0; i < 2; ++i) {
            const int c = tid + i * 256;
            *(bf16x8*)(As + (c >> 3) * 72 + (c & 7) * 8) = va[i];
            *(bf16x8*)(Bs + (c >> 3) * 72 + (c & 7) * 8) = vbv[i];
        }
        __syncthreads();
#pragma unroll
        for (int kk = 0; kk < 2; ++kk) {
            bf16x8 af, bfr[4];
            af = *(const bf16x8*)(As + (w * 16 + lid) * 72 + kk * 32 + grp * 8);
#pragma unroll
            for (int n = 0; n < 4; ++n)
                bfr[n] = *(const bf16x8*)(Bs + (n * 16 + lid) * 72 + kk * 32 + grp * 8);
#pragma unroll
            for (int n = 0; n < 4; ++n)
                acc[n] = __builtin_amdgcn_mfma_f32_16x16x32_bf16(af, bfr[n], acc[n], 0, 0, 0);
        }
    }
    float wsm[4] = {1.f, 1.f, 1.f, 1.f};
    if (isq) {
        float s0 = sw[0], s1 = sw[1], s2 = sw[2], s3 = sw[3];
        float mx = fmaxf(fmaxf(s0, s1), fmaxf(s2, s3));
        float e0 = expf(s0 - mx), e1 = expf(s1 - mx), e2 = expf(s2 - mx), e3 = expf(s3 - mx);
        float inv = 1.0f / (e0 + e1 + e2 + e3);
        wsm[0] = e0 * inv; wsm[1] = e1 * inv; wsm[2] = e2 * inv; wsm[3] = e3 * inv;
    }
#pragma unroll
    for (int n = 0; n < 4; ++n) {
        const int p = n * 16 + lid;
        const float bc = b2[p];
        const float wg = isq ? wsm[p >> 4] : 1.0f;
#pragma unroll
        for (int r = 0; r < 4; ++r) {
            const int row = row0 + w * 16 + grp * 4 + r;
            float u = acc[n][r] + bc;
            float ph = tanhf(u) * PI_F;
            float sp, cp;
            sincosf(ph, &sp, &cp);
            const unsigned short cb = f2bf(cp * wg), sb = f2bf(sp * wg);
            FROW[(size_t)row * FF + 2 * p + 0] = cb;
            FROW[(size_t)row * FF + 2 * p + 1] = sb;
            if (!isq) {
                const int b = row >> 11, l = row & (LQ - 1);
                const int c = l >> 6, t = l & 63;
                const size_t base = ((size_t)(b * NC + c) * FF) * TC;
                CKt[base + (size_t)(2 * p + 0) * TC + t] = cb;
                CKt[base + (size_t)(2 * p + 1) * TC + t] = sb;
            }
        }
    }
}

// ---------------- pass A: per-chunk state (bf16) Stp[b][c][d][f] = sum_t Vt[d][t]*CKt[f][t] ----------------
__global__ __launch_bounds__(256) void passA_mfma(
    const unsigned short* __restrict__ Vt, const unsigned short* __restrict__ CKt,
    unsigned short* __restrict__ Stp)
{
    const int tid = threadIdx.x;
    const int w = tid >> 6, lane = tid & 63, grp = lane >> 4, lid = lane & 15;
    const int dq = blockIdx.x, c = blockIdx.y, b = blockIdx.z;
    const int d0 = dq * 128 + w * 32;
    const size_t cb = (size_t)(b * NC + c);
    f32x4 acc[2][8];
#pragma unroll
    for (int md = 0; md < 2; ++md)
#pragma unroll
        for (int nf = 0; nf < 8; ++nf) acc[md][nf] = (f32x4)0.f;
#pragma unroll
    for (int kt = 0; kt < 2; ++kt) {
        bf16x8 av[2], bk[8];
#pragma unroll
        for (int md = 0; md < 2; ++md)
            av[md] = *(const bf16x8*)(Vt + (cb * DD + d0 + md * 16 + lid) * TC + kt * 32 + grp * 8);
#pragma unroll
        for (int nf = 0; nf < 8; ++nf)
            bk[nf] = *(const bf16x8*)(CKt + (cb * FF + nf * 16 + lid) * TC + kt * 32 + grp * 8);
#pragma unroll
        for (int md = 0; md < 2; ++md)
#pragma unroll
            for (int nf = 0; nf < 8; ++nf)
                acc[md][nf] = __builtin_amdgcn_mfma_f32_16x16x32_bf16(av[md], bk[nf], acc[md][nf], 0, 0, 0);
    }
#pragma unroll
    for (int md = 0; md < 2; ++md)
#pragma unroll
        for (int nf = 0; nf < 8; ++nf)
#pragma unroll
            for (int r = 0; r < 4; ++r) {
                const int d = d0 + md * 16 + grp * 4 + r;
                const int f = nf * 16 + lid;
                Stp[(cb * DD + d) * FF + f] = f2bf(acc[md][nf][r]);
            }
}

// ---------------- pass B: exclusive prefix over chunks (bf16 in, f32 run, bf16 out) ----------------
__global__ __launch_bounds__(256) void prefix_mfma(
    const unsigned short* __restrict__ Stp, unsigned short* __restrict__ Stb)
{
    const int gid = blockIdx.x * 256 + threadIdx.x;  // b*(DD*FF) + d*FF + f
    const int b = gid >> 16;                          // DD*FF = 65536
    const int df = gid & 65535;
    float run = 0.f;
#pragma unroll
    for (int c = 0; c < NC; ++c) {
        const size_t idx = ((size_t)(b * NC + c) << 16) + df;
        Stb[idx] = f2bf(run);
        run += bf2f(Stp[idx]);
    }
}

// ---------------- pass C: r = tril(CQ CK^T) V + CQ S_prefix ----------------
__global__ __launch_bounds__(128) void passC_mfma(
    const unsigned short* __restrict__ CQb, const unsigned short* __restrict__ CKb,
    const unsigned short* __restrict__ Vt, const unsigned short* __restrict__ Stb,
    float* __restrict__ R)
{
    __shared__ unsigned short P[64][72];
    const int tid = threadIdx.x;
    const int w = tid >> 6, lane = tid & 63, grp = lane >> 4, lid = lane & 15;
    const int dh = blockIdx.x, c = blockIdx.y, b = blockIdx.z;
    const size_t rowbase = (size_t)b * LQ + c * 64;
    const size_t cb = (size_t)(b * NC + c);
    f32x4 qk[2][4];
#pragma unroll
    for (int mi = 0; mi < 2; ++mi)
#pragma unroll
        for (int nt = 0; nt < 4; ++nt) qk[mi][nt] = (f32x4)0.f;
#pragma unroll
    for (int kf = 0; kf < 4; ++kf) {
        bf16x8 aq[2], bk[4];
#pragma unroll
        for (int mi = 0; mi < 2; ++mi)
            aq[mi] = *(const bf16x8*)(CQb + (rowbase + (2 * w + mi) * 16 + lid) * FF + kf * 32 + grp * 8);
#pragma unroll
        for (int nt = 0; nt < 4; ++nt)
            bk[nt] = *(const bf16x8*)(CKb + (rowbase + nt * 16 + lid) * FF + kf * 32 + grp * 8);
#pragma unroll
        for (int mi = 0; mi < 2; ++mi)
#pragma unroll
            for (int nt = 0; nt < 4; ++nt)
                qk[mi][nt] = __builtin_amdgcn_mfma_f32_16x16x32_bf16(aq[mi], bk[nt], qk[mi][nt], 0, 0, 0);
    }
#pragma unroll
    for (int mi = 0; mi < 2; ++mi)
#pragma unroll
        for (int nt = 0; nt < 4; ++nt)
#pragma unroll
            for (int r = 0; r < 4; ++r) {
                const int row = (2 * w + mi) * 16 + grp * 4 + r;
                const int col = nt * 16 + lid;
                P[row][col] = f2bf(col <= row ? qk[mi][nt][r] : 0.f);
            }
    __syncthreads();
    const int d0 = dh * 128 + w * 64;
    f32x4 racc[4][4];
#pragma unroll
    for (int ml = 0; ml < 4; ++ml)
#pragma unroll
        for (int nd = 0; nd < 4; ++nd) racc[ml][nd] = (f32x4)0.f;
#pragma unroll
    for (int kt = 0; kt < 2; ++kt) {
        bf16x8 ap[4], bv[4];
#pragma unroll
        for (int ml = 0; ml < 4; ++ml)
            ap[ml] = *(const bf16x8*)&P[ml * 16 + lid][kt * 32 + grp * 8];
#pragma unroll
        for (int nd = 0; nd < 4; ++nd)
            bv[nd] = *(const bf16x8*)(Vt + (cb * DD + d0 + nd * 16 + lid) * TC + kt * 32 + grp * 8);
#pragma unroll
        for (int ml = 0; ml < 4; ++ml)
#pragma unroll
            for (int nd = 0; nd < 4; ++nd)
                racc[ml][nd] = __builtin_amdgcn_mfma_f32_16x16x32_bf16(ap[ml], bv[nd], racc[ml][nd], 0, 0, 0);
    }
#pragma unroll
    for (int kf = 0; kf < 4; ++kf) {
        bf16x8 aq[4], bs[4];
#pragma unroll
        for (int ml = 0; ml < 4; ++ml)
            aq[ml] = *(const bf16x8*)(CQb + (rowbase + ml * 16 + lid) * FF + kf * 32 + grp * 8);
#pragma unroll
        for (int nd = 0; nd < 4; ++nd)
            bs[nd] = *(const bf16x8*)(Stb + (cb * DD + d0 + nd * 16 + lid) * FF + kf * 32 + grp * 8);
#pragma unroll
        for (int ml = 0; ml < 4; ++ml)
#pragma unroll
            for (int nd = 0; nd < 4; ++nd)
                racc[ml][nd] = __builtin_amdgcn_mfma_f32_16x16x32_bf16(aq[ml], bs[nd], racc[ml][nd], 0, 0, 0);
    }
#pragma unroll
    for (int ml = 0; ml < 4; ++ml)
#pragma unroll
        for (int nd = 0; nd < 4; ++nd)
#pragma unroll
            for (int r = 0; r < 4; ++r) {
                const int l = ml * 16 + grp * 4 + r;
                const int d = d0 + nd * 16 + lid;
                R[(rowbase + l) * DD + d] = racc[ml][nd][r];
            }
}

// ---------------- position norm + LayerNorm (bf16 out) ----------------
__global__ __launch_bounds__(256) void ln_kernel(
    const float* __restrict__ R, const float* __restrict__ g,
    const float* __restrict__ be, unsigned short* __restrict__ YN)
{
    const int row = blockIdx.x;
    const int l = row & (LQ - 1);
    const int tid = threadIdx.x;
    const float pscale = rsqrtf((float)((l + 1) * PPL));
    float y0 = R[(size_t)row * DD + tid] * pscale;
    float y1 = R[(size_t)row * DD + 256 + tid] * pscale;
    float s = y0 + y1;
    float q = y0 * y0 + y1 * y1;
#pragma unroll
    for (int off = 32; off >= 1; off >>= 1) {
        s += __shfl_xor(s, off, 64);
        q += __shfl_xor(q, off, 64);
    }
    __shared__ float rs[4], rq[4];
    const int wid = tid >> 6, lane = tid & 63;
    if (lane == 0) { rs[wid] = s; rq[wid] = q; }
    __syncthreads();
    const float ts = rs[0] + rs[1] + rs[2] + rs[3];
    const float tq = rq[0] + rq[1] + rq[2] + rq[3];
    const float mu = ts * (1.0f / DD);
    float var = tq * (1.0f / DD) - mu * mu;
    const float rstd = rsqrtf(var + 1e-5f);
    YN[(size_t)row * DD + tid] = f2bf((y0 - mu) * rstd * g[tid] + be[tid]);
    YN[(size_t)row * DD + 256 + tid] = f2bf((y1 - mu) * rstd * g[tid + 256] + be[tid + 256]);
}

// ---------------- output GEMM: BM=64, BN=64 (4 waves of 32x32), out = acc + bias + resid ----------------
__global__ __launch_bounds__(256) void mgemm_out(
    const unsigned short* __restrict__ A, const unsigned short* __restrict__ Bt,
    const float* __restrict__ bias, const float* __restrict__ resid,
    float* __restrict__ out)
{
    const int K = DD, N = DD;
    __shared__ unsigned short As[64 * 72];
    __shared__ unsigned short Bs[64 * 72];
    const int tid = threadIdx.x;
    const int w = tid >> 6, lane = tid & 63, grp = lane >> 4, lid = lane & 15;
    const int wr = w >> 1, wc = w & 1;
    const int row0 = blockIdx.y * 64, col0 = blockIdx.x * 64;
    f32x4 acc[2][2];
#pragma unroll
    for (int m = 0; m < 2; ++m)
#pragma unroll
        for (int n = 0; n < 2; ++n) acc[m][n] = (f32x4)0.f;

    for (int k0 = 0; k0 < K; k0 += 64) {
        bf16x8 va[2], vbv[2];
#pragma unroll
        for (int i = 0; i < 2; ++i) {
            const int c = tid + i * 256;
            va[i] = *(const bf16x8*)(A + (size_t)(row0 + (c >> 3)) * K + k0 + (c & 7) * 8);
            vbv[i] = *(const bf16x8*)(Bt + (size_t)(col0 + (c >> 3)) * K + k0 + (c & 7) * 8);
        }
        __syncthreads();
#pragma unroll
        for (int i = 0; i < 2; ++i) {
            const int c = tid + i * 256;
            *(bf16x8*)(As + (c >> 3) * 72 + (c & 7) * 8) = va[i];
            *(bf16x8*)(Bs + (c >> 3) * 72 + (c & 7) * 8) = vbv[i];
        }
        __syncthreads();
#pragma unroll
        for (int kk = 0; kk < 2; ++kk) {
            bf16x8 af[2], bfr[2];
#pragma unroll
            for (int m = 0; m < 2; ++m)
                af[m] = *(const bf16x8*)(As + (wr * 32 + m * 16 + lid) * 72 + kk * 32 + grp * 8);
#pragma unroll
            for (int n = 0; n < 2; ++n)
                bfr[n] = *(const bf16x8*)(Bs + (wc * 32 + n * 16 + lid) * 72 + kk * 32 + grp * 8);
#pragma unroll
            for (int m = 0; m < 2; ++m)
#pragma unroll
                for (int n = 0; n < 2; ++n)
                    acc[m][n] = __builtin_amdgcn_mfma_f32_16x16x32_bf16(af[m], bfr[n], acc[m][n], 0, 0, 0);
        }
    }
#pragma unroll
    for (int m = 0; m < 2; ++m) {
#pragma unroll
        for (int n = 0; n < 2; ++n) {
            const int col = col0 + wc * 32 + n * 16 + lid;
            const float bc = bias[col];
#pragma unroll
            for (int r = 0; r < 4; ++r) {
                const int row = row0 + wr * 32 + m * 16 + grp * 4 + r;
                out[(size_t)row * N + col] = acc[m][n][r] + bc + resid[(size_t)row * N + col];
            }
        }
    }
}

extern "C" void kernel_launch(void* const* d_in, const int* in_sizes, int n_in,
                              void* d_out, int out_size, void* d_ws, size_t ws_size,
                              hipStream_t stream)
{
    const float* x   = (const float*)d_in[0];
    const float* sw  = (const float*)d_in[1];
    const float* kw1 = (const float*)d_in[2];
    const float* kb1 = (const float*)d_in[3];
    const float* kw2 = (const float*)d_in[4];
    const float* kb2 = (const float*)d_in[5];
    const float* qw1 = (const float*)d_in[6];
    const float* qb1 = (const float*)d_in[7];
    const float* qw2 = (const float*)d_in[8];
    const float* qb2 = (const float*)d_in[9];
    const float* vw  = (const float*)d_in[10];
    const float* vb  = (const float*)d_in[11];
    const float* lng = (const float*)d_in[12];
    const float* lnb = (const float*)d_in[13];
    const float* ow  = (const float*)d_in[14];
    const float* ob  = (const float*)d_in[15];
    float* out = (float*)d_out;

    const size_t MR = (size_t)NB * LQ;  // 4096 rows
    float* ws = (float*)d_ws;
    float* Rb = ws;                                   // 2M f32
    unsigned short* xb   = (unsigned short*)(Rb + MR * DD);
    unsigned short* hkb  = xb + MR * DD;
    unsigned short* hqb  = hkb + MR * DD;
    unsigned short* YNb  = hqb + MR * DD;
    unsigned short* Vt   = YNb + MR * DD;
    unsigned short* CQb  = Vt + MR * DD;
    unsigned short* CKb  = CQb + MR * FF;
    unsigned short* CKt  = CKb + MR * FF;
    unsigned short* Stp  = CKt + MR * FF;             // 4M shorts
    unsigned short* Stb  = Stp + (size_t)NB * NC * DD * FF;  // 4M shorts
    unsigned short* kw1t = Stb + (size_t)NB * NC * DD * FF;
    unsigned short* qw1t = kw1t + (size_t)DD * DD;
    unsigned short* vwt  = qw1t + (size_t)DD * DD;
    unsigned short* owt  = vwt + (size_t)DD * DD;
    unsigned short* kw2t = owt + (size_t)DD * DD;
    unsigned short* qw2t = kw2t + (size_t)TPP * DD;

    const dim3 blk(256);
    hipLaunchKernelGGL(cast_bf16, dim3((unsigned)(MR * DD / 2048)), blk, 0, stream, x, xb, (int)(MR * DD));
    hipLaunchKernelGGL(wtrans_kernel, dim3(16, 16, 4), blk, 0, stream,
                       kw1, qw1, vw, ow, kw1t, qw1t, vwt, owt, DD, DD);
    hipLaunchKernelGGL(wtrans_kernel, dim3(2, 16, 2), blk, 0, stream,
                       kw2, qw2, kw2, qw2, kw2t, qw2t, kw2t, qw2t, DD, TPP);

    hipLaunchKernelGGL(mgemm_fused, dim3(DD / 64, MR / 128, 3), blk, 0, stream,
                       xb, kw1t, qw1t, vwt, kb1, qb1, vb, hkb, hqb, Vt);
    hipLaunchKernelGGL(phase_fused, dim3(MR / 64, 2), blk, 0, stream,
                       hkb, hqb, kw2t, qw2t, kb2, qb2, sw, CKb, CQb, CKt);

    hipLaunchKernelGGL(passA_mfma, dim3(4, NC, NB), blk, 0, stream, Vt, CKt, Stp);
    hipLaunchKernelGGL(prefix_mfma, dim3((NB * DD * FF) / 256), blk, 0, stream, Stp, Stb);
    hipLaunchKernelGGL(passC_mfma, dim3(4, NC, NB), dim3(128), 0, stream, CQb, CKb, Vt, Stb, Rb);
    hipLaunchKernelGGL(ln_kernel, dim3((unsigned)MR), blk, 0, stream, Rb, lng, lnb, YNb);
    hipLaunchKernelGGL(mgemm_out, dim3(DD / 64, MR / 64), blk, 0, stream, YNb, owt, ob, x, out);
}